// Round 1
// baseline (133.129 us; speedup 1.0000x reference)
//
#include <hip/hip_runtime.h>

#define N 4096
#define TSTEPS 3
#define FEAT 36
#define NVIS 6
#define HID 256
#define DIN 18   // TSTEPS*NVIS
#define DOUT 2

#define JT 512      // j-tile staged in LDS
#define XPITCH 20   // padded pitch (floats) -> 80B rows, 16B aligned

// ---------------- Kernel 1: xall[j][t*6+c] = vis[j,t,:] @ W_vis + b_vis ----
__global__ void k_vis(const float* __restrict__ vis, const float* __restrict__ Wv,
                      const float* __restrict__ bv, float* __restrict__ xall) {
    int o = blockIdx.x * blockDim.x + threadIdx.x;
    if (o >= N * DIN) return;
    int j  = o / DIN;
    int ct = o - j * DIN;
    int t  = ct / NVIS;
    int c  = ct - t * NVIS;
    const float* vrow = vis + (size_t)j * (TSTEPS * FEAT) + t * FEAT;
    float acc = bv[c];
#pragma unroll
    for (int f = 0; f < FEAT; ++f) acc += vrow[f] * Wv[f * NVIS + c];
    xall[o] = acc;
}

// ---------------- Kernel 2: fused 3-timestep message pass -------------------
// Each block: 4 waves, each wave owns 2 rows. One streaming pass over a_nets.
__global__ void k_msg(const float* __restrict__ a, const float* __restrict__ xall,
                      float* __restrict__ xagg) {
    __shared__ float xpad[JT][XPITCH];
    const int tid  = threadIdx.x;
    const int lane = tid & 63;
    const int wave = tid >> 6;
    const int row_base = blockIdx.x * 8 + wave * 2;

    const float* a0 = a + (size_t)row_base       * (N * 3);
    const float* a1 = a + (size_t)(row_base + 1) * (N * 3);

    float acc[2][3][6];   // [row][t][c]
    float s[2][2];        // [row][{s1,s2}]
#pragma unroll
    for (int r = 0; r < 2; ++r) {
#pragma unroll
        for (int t = 0; t < 3; ++t)
#pragma unroll
            for (int c = 0; c < 6; ++c) acc[r][t][c] = 0.f;
        s[r][0] = 0.f; s[r][1] = 0.f;
    }

    for (int tile = 0; tile < N / JT; ++tile) {
        const int tb = tile * JT;
        __syncthreads();
        // stage x tile: 512 x 18 floats
        for (int idx = tid; idx < JT * DIN; idx += 256) {
            int jj = idx / DIN;
            int c  = idx - jj * DIN;
            xpad[jj][c] = xall[(size_t)(tb + jj) * DIN + c];
        }
        __syncthreads();

#pragma unroll
        for (int chunk = 0; chunk < JT / 256; ++chunk) {
            const int jj = chunk * 256 + lane * 4;   // 4 consecutive j per lane
            const size_t jb = (size_t)(tb + jj) * 3; // 12-float group, 48B aligned
            const float4* pa0 = (const float4*)(a0 + jb);
            const float4* pa1 = (const float4*)(a1 + jb);
            float4 u0 = pa0[0], u1 = pa0[1], u2 = pa0[2];
            float4 v0 = pa1[0], v1 = pa1[1], v2 = pa1[2];
            const float av0[4][3] = {{u0.x,u0.y,u0.z},{u0.w,u1.x,u1.y},
                                     {u1.z,u1.w,u2.x},{u2.y,u2.z,u2.w}};
            const float av1[4][3] = {{v0.x,v0.y,v0.z},{v0.w,v1.x,v1.y},
                                     {v1.z,v1.w,v2.x},{v2.y,v2.z,v2.w}};
#pragma unroll
            for (int q = 0; q < 4; ++q) {
                const float* xr = &xpad[jj + q][0];
                float4 x0 = *(const float4*)(xr);
                float4 x1 = *(const float4*)(xr + 4);
                float4 x2 = *(const float4*)(xr + 8);
                float4 x3 = *(const float4*)(xr + 12);
                const float xv[18] = {x0.x,x0.y,x0.z,x0.w, x1.x,x1.y,x1.z,x1.w,
                                      x2.x,x2.y,x2.z,x2.w, x3.x,x3.y,x3.z,x3.w,
                                      xr[16], xr[17]};
#pragma unroll
                for (int t = 0; t < 3; ++t)
#pragma unroll
                    for (int c = 0; c < 6; ++c) {
                        acc[0][t][c] += av0[q][t] * xv[t*6+c];
                        acc[1][t][c] += av1[q][t] * xv[t*6+c];
                    }
                s[0][0] += av0[q][1]; s[0][1] += av0[q][2];
                s[1][0] += av1[q][1]; s[1][1] += av1[q][2];
            }
        }
    }

    // butterfly reduce across the 64 lanes
#pragma unroll
    for (int m = 1; m < 64; m <<= 1) {
#pragma unroll
        for (int r = 0; r < 2; ++r) {
#pragma unroll
            for (int t = 0; t < 3; ++t)
#pragma unroll
                for (int c = 0; c < 6; ++c)
                    acc[r][t][c] += __shfl_xor(acc[r][t][c], m, 64);
            s[r][0] += __shfl_xor(s[r][0], m, 64);
            s[r][1] += __shfl_xor(s[r][1], m, 64);
        }
    }

    if (lane == 0) {
#pragma unroll
        for (int r = 0; r < 2; ++r) {
            const float s1 = s[r][0], s2 = s[r][1];
            float* orow = xagg + (size_t)(row_base + r) * DIN;
#pragma unroll
            for (int c = 0; c < 6; ++c) {
                orow[c]      = acc[r][2][c];
                orow[6 + c]  = acc[r][1][c] * s2;
                orow[12 + c] = acc[r][0][c] * s1 * s2;
            }
        }
    }
}

// ---------------- Kernel 3: MLP 18->256->256->256->2 ------------------------
// 16 rows/block. Thread c owns output neuron c for all 16 rows.
// Hidden activations stored k-major [k][16] so per-k reads are uniform float4s.
__global__ void k_mlp(const float* __restrict__ xagg,
                      const float* __restrict__ W0, const float* __restrict__ b0,
                      const float* __restrict__ W1, const float* __restrict__ b1,
                      const float* __restrict__ W2, const float* __restrict__ b2,
                      const float* __restrict__ Wp, const float* __restrict__ bp,
                      float* __restrict__ u_out) {
    __shared__ float xa[16][DIN];
    __shared__ float hb[2][HID][16];
    const int tid  = threadIdx.x;
    const int base = blockIdx.x * 16;

    for (int idx = tid; idx < 16 * DIN; idx += 256) {
        int r = idx / DIN, e = idx - r * DIN;
        xa[r][e] = xagg[(size_t)(base + r) * DIN + e];
    }
    __syncthreads();

    { // layer 0: 18 -> 256, relu
        float accv[16];
#pragma unroll
        for (int r = 0; r < 16; ++r) accv[r] = b0[tid];
        for (int k = 0; k < DIN; ++k) {
            float w = W0[k * HID + tid];
#pragma unroll
            for (int r = 0; r < 16; ++r) accv[r] += xa[r][k] * w;
        }
#pragma unroll
        for (int r = 0; r < 16; ++r) hb[0][tid][r] = fmaxf(accv[r], 0.f);
    }
    __syncthreads();

    { // layer 1: 256 -> 256, relu  (read hb[0], write hb[1])
        float accv[16];
#pragma unroll
        for (int r = 0; r < 16; ++r) accv[r] = b1[tid];
        for (int k = 0; k < HID; ++k) {
            float w = W1[k * HID + tid];
            const float4* hp = (const float4*)&hb[0][k][0];
            float4 h0 = hp[0], h1 = hp[1], h2 = hp[2], h3 = hp[3];
            const float hv[16] = {h0.x,h0.y,h0.z,h0.w, h1.x,h1.y,h1.z,h1.w,
                                  h2.x,h2.y,h2.z,h2.w, h3.x,h3.y,h3.z,h3.w};
#pragma unroll
            for (int r = 0; r < 16; ++r) accv[r] += hv[r] * w;
        }
#pragma unroll
        for (int r = 0; r < 16; ++r) hb[1][tid][r] = fmaxf(accv[r], 0.f);
    }
    __syncthreads();

    { // layer 2: 256 -> 256, relu  (read hb[1], write hb[0])
        float accv[16];
#pragma unroll
        for (int r = 0; r < 16; ++r) accv[r] = b2[tid];
        for (int k = 0; k < HID; ++k) {
            float w = W2[k * HID + tid];
            const float4* hp = (const float4*)&hb[1][k][0];
            float4 h0 = hp[0], h1 = hp[1], h2 = hp[2], h3 = hp[3];
            const float hv[16] = {h0.x,h0.y,h0.z,h0.w, h1.x,h1.y,h1.z,h1.w,
                                  h2.x,h2.y,h2.z,h2.w, h3.x,h3.y,h3.z,h3.w};
#pragma unroll
            for (int r = 0; r < 16; ++r) accv[r] += hv[r] * w;
        }
#pragma unroll
        for (int r = 0; r < 16; ++r) hb[0][tid][r] = fmaxf(accv[r], 0.f);
    }
    __syncthreads();

    // final: 256 -> 2
    if (tid < 32) {
        int r = tid >> 1, d = tid & 1;
        float acc = bp[d];
        for (int k = 0; k < HID; ++k) acc += hb[0][k][r] * Wp[k * DOUT + d];
        u_out[(size_t)(base + r) * DOUT + d] = acc;
    }
}

extern "C" void kernel_launch(void* const* d_in, const int* in_sizes, int n_in,
                              void* d_out, int out_size, void* d_ws, size_t ws_size,
                              hipStream_t stream) {
    const float* vis  = (const float*)d_in[0];
    const float* anet = (const float*)d_in[1];
    const float* Wv   = (const float*)d_in[2];
    const float* bv   = (const float*)d_in[3];
    const float* W0   = (const float*)d_in[4];
    const float* b0   = (const float*)d_in[5];
    const float* W1   = (const float*)d_in[6];
    const float* b1   = (const float*)d_in[7];
    const float* W2   = (const float*)d_in[8];
    const float* b2   = (const float*)d_in[9];
    const float* Wp   = (const float*)d_in[10];
    const float* bp   = (const float*)d_in[11];

    float* xagg  = (float*)d_out;                  // 4096*18
    float* u_out = (float*)d_out + (size_t)N*DIN;  // 4096*2
    float* xall  = (float*)d_ws;                   // 4096*18 scratch

    k_vis<<<(N * DIN + 255) / 256, 256, 0, stream>>>(vis, Wv, bv, xall);
    k_msg<<<N / 8, 256, 0, stream>>>(anet, xall, xagg);
    k_mlp<<<N / 16, 256, 0, stream>>>(xagg, W0, b0, W1, b1, W2, b2, Wp, bp, u_out);
}

// Round 3
// 97.357 us; speedup vs baseline: 1.3674x; 1.3674x over previous
//
#include <hip/hip_runtime.h>

#define N 4096
#define TSTEPS 3
#define FEAT 36
#define NVIS 6
#define HID 256
#define DIN 18   // TSTEPS*NVIS
#define DOUT 2

#define JT 512      // j-tile staged in LDS

// Collision-free skewed LDS offset. Each 32-row block gets a 672-dword arena:
//   o(r) = (r>>5)*672 + (r&31)*20 + ((r>>2)&7)*4
// - rows never overlap (worst case 620+28+18=666 <= 672)
// - 672 % 32 == 0, so lane i (row 4i) starts at dword (i&7)*84 = (i&7)*20 mod 32
//   -> 8 starts {0,4,...,28}: 8 consecutive lanes' b128 reads tile all 32 banks
//   exactly once -> 2-way max = free (m136)
// - every offset is a multiple of 4 dwords -> 16B-aligned b128/b64
__device__ __forceinline__ int srow(int r) {
    return (r >> 5) * 672 + (r & 31) * 20 + ((r >> 2) & 7) * 4;
}

// ---------------- Kernel 1: xall[j][t*6+c] = vis[j,t,:] @ W_vis + b_vis ----
__global__ void k_vis(const float* __restrict__ vis, const float* __restrict__ Wv,
                      const float* __restrict__ bv, float* __restrict__ xall) {
    int o = blockIdx.x * blockDim.x + threadIdx.x;
    if (o >= N * DIN) return;
    int j  = o / DIN;
    int ct = o - j * DIN;
    int t  = ct / NVIS;
    int c  = ct - t * NVIS;
    const float* vrow = vis + (size_t)j * (TSTEPS * FEAT) + t * FEAT;
    float acc = bv[c];
#pragma unroll
    for (int f = 0; f < FEAT; ++f) acc += vrow[f] * Wv[f * NVIS + c];
    xall[o] = acc;
}

// ---------------- Kernel 2: fused 3-timestep message pass -------------------
// 512 blocks x 256 thr; each wave owns 2 rows; one streaming pass over a_nets.
__global__ void k_msg(const float* __restrict__ a, const float* __restrict__ xall,
                      float* __restrict__ xagg) {
    __shared__ float xs[16 * 672];   // 43 KB, srow(511)+18 = 10746 <= 10752
    const int tid  = threadIdx.x;
    const int lane = tid & 63;
    const int wave = tid >> 6;
    const int row_base = blockIdx.x * 8 + wave * 2;

    const float* a0 = a + (size_t)row_base       * (N * 3);
    const float* a1 = a + (size_t)(row_base + 1) * (N * 3);

    float acc[2][3][6];   // [row][t][c]
    float s[2][2];        // [row][{s1,s2}]
#pragma unroll
    for (int r = 0; r < 2; ++r) {
#pragma unroll
        for (int t = 0; t < 3; ++t)
#pragma unroll
            for (int c = 0; c < 6; ++c) acc[r][t][c] = 0.f;
        s[r][0] = 0.f; s[r][1] = 0.f;
    }

    for (int tile = 0; tile < N / JT; ++tile) {
        const int tb = tile * JT;
        __syncthreads();
        // stage x tile: 512 rows x 18 floats, skewed layout
        for (int idx = tid; idx < JT * DIN; idx += 256) {
            int jj = idx / DIN;
            int c  = idx - jj * DIN;
            xs[srow(jj) + c] = xall[(size_t)(tb + jj) * DIN + c];
        }
        __syncthreads();

#pragma unroll
        for (int chunk = 0; chunk < JT / 256; ++chunk) {
            const int jj = chunk * 256 + lane * 4;   // 4 consecutive j per lane
            const size_t jb = (size_t)(tb + jj) * 3; // 12-float group, 48B aligned
            const float4* pa0 = (const float4*)(a0 + jb);
            const float4* pa1 = (const float4*)(a1 + jb);
            float4 u0 = pa0[0], u1 = pa0[1], u2 = pa0[2];
            float4 v0 = pa1[0], v1 = pa1[1], v2 = pa1[2];
            const float av0[4][3] = {{u0.x,u0.y,u0.z},{u0.w,u1.x,u1.y},
                                     {u1.z,u1.w,u2.x},{u2.y,u2.z,u2.w}};
            const float av1[4][3] = {{v0.x,v0.y,v0.z},{v0.w,v1.x,v1.y},
                                     {v1.z,v1.w,v2.x},{v2.y,v2.z,v2.w}};
#pragma unroll
            for (int q = 0; q < 4; ++q) {
                const float* xr = xs + srow(jj + q);
                float4 x0 = *(const float4*)(xr);
                float4 x1 = *(const float4*)(xr + 4);
                float4 x2 = *(const float4*)(xr + 8);
                float4 x3 = *(const float4*)(xr + 12);
                const float xv[18] = {x0.x,x0.y,x0.z,x0.w, x1.x,x1.y,x1.z,x1.w,
                                      x2.x,x2.y,x2.z,x2.w, x3.x,x3.y,x3.z,x3.w,
                                      xr[16], xr[17]};
#pragma unroll
                for (int t = 0; t < 3; ++t)
#pragma unroll
                    for (int c = 0; c < 6; ++c) {
                        acc[0][t][c] += av0[q][t] * xv[t*6+c];
                        acc[1][t][c] += av1[q][t] * xv[t*6+c];
                    }
                s[0][0] += av0[q][1]; s[0][1] += av0[q][2];
                s[1][0] += av1[q][1]; s[1][1] += av1[q][2];
            }
        }
    }

    // butterfly reduce across the 64 lanes
#pragma unroll
    for (int m = 1; m < 64; m <<= 1) {
#pragma unroll
        for (int r = 0; r < 2; ++r) {
#pragma unroll
            for (int t = 0; t < 3; ++t)
#pragma unroll
                for (int c = 0; c < 6; ++c)
                    acc[r][t][c] += __shfl_xor(acc[r][t][c], m, 64);
            s[r][0] += __shfl_xor(s[r][0], m, 64);
            s[r][1] += __shfl_xor(s[r][1], m, 64);
        }
    }

    if (lane == 0) {
#pragma unroll
        for (int r = 0; r < 2; ++r) {
            const float s1 = s[r][0], s2 = s[r][1];
            float* orow = xagg + (size_t)(row_base + r) * DIN;
#pragma unroll
            for (int c = 0; c < 6; ++c) {
                orow[c]      = acc[r][2][c];
                orow[6 + c]  = acc[r][1][c] * s2;
                orow[12 + c] = acc[r][0][c] * s1 * s2;
            }
        }
    }
}

// ---------------- Kernel 3: MLP 18->256->256->256->2 ------------------------
// 256 blocks x 512 thr (8 waves -> 2 waves/SIMD). 16 rows/block.
// Threads 0-255 handle rows 0-7 for all 256 neurons; threads 256-511 rows 8-15.
// Hidden acts k-major [k][20-pitch] so per-k reads are uniform aligned float4s.
#define HPITCH 20
__global__ __launch_bounds__(512, 2) void k_mlp(const float* __restrict__ xagg,
                      const float* __restrict__ W0, const float* __restrict__ b0,
                      const float* __restrict__ W1, const float* __restrict__ b1,
                      const float* __restrict__ W2, const float* __restrict__ b2,
                      const float* __restrict__ Wp, const float* __restrict__ bp,
                      float* __restrict__ u_out) {
    __shared__ float xa[16][DIN];
    __shared__ float hb[2][HID][HPITCH];
    const int tid   = threadIdx.x;
    const int n     = tid & 255;   // neuron
    const int rbase = (tid >> 8) * 8;
    const int base  = blockIdx.x * 16;

    for (int idx = tid; idx < 16 * DIN; idx += 512) {
        int r = idx / DIN, e = idx - r * DIN;
        xa[r][e] = xagg[(size_t)(base + r) * DIN + e];
    }
    __syncthreads();

    { // layer 0: 18 -> 256, relu
        float accv[8];
#pragma unroll
        for (int r = 0; r < 8; ++r) accv[r] = b0[n];
        for (int k = 0; k < DIN; ++k) {
            float w = W0[k * HID + n];
#pragma unroll
            for (int r = 0; r < 8; ++r) accv[r] += xa[rbase + r][k] * w;
        }
#pragma unroll
        for (int r = 0; r < 8; ++r) hb[0][n][rbase + r] = fmaxf(accv[r], 0.f);
    }
    __syncthreads();

    { // layer 1: 256 -> 256, relu  (read hb[0], write hb[1])
        float accv[8];
#pragma unroll
        for (int r = 0; r < 8; ++r) accv[r] = b1[n];
        for (int k = 0; k < HID; ++k) {
            float w = W1[k * HID + n];
            const float4* hp = (const float4*)&hb[0][k][rbase];
            float4 h0 = hp[0], h1 = hp[1];
            const float hv[8] = {h0.x,h0.y,h0.z,h0.w, h1.x,h1.y,h1.z,h1.w};
#pragma unroll
            for (int r = 0; r < 8; ++r) accv[r] += hv[r] * w;
        }
#pragma unroll
        for (int r = 0; r < 8; ++r) hb[1][n][rbase + r] = fmaxf(accv[r], 0.f);
    }
    __syncthreads();

    { // layer 2: 256 -> 256, relu  (read hb[1], write hb[0])
        float accv[8];
#pragma unroll
        for (int r = 0; r < 8; ++r) accv[r] = b2[n];
        for (int k = 0; k < HID; ++k) {
            float w = W2[k * HID + n];
            const float4* hp = (const float4*)&hb[1][k][rbase];
            float4 h0 = hp[0], h1 = hp[1];
            const float hv[8] = {h0.x,h0.y,h0.z,h0.w, h1.x,h1.y,h1.z,h1.w};
#pragma unroll
            for (int r = 0; r < 8; ++r) accv[r] += hv[r] * w;
        }
#pragma unroll
        for (int r = 0; r < 8; ++r) hb[0][n][rbase + r] = fmaxf(accv[r], 0.f);
    }
    __syncthreads();

    // final: 256 -> 2
    if (tid < 32) {
        int r = tid >> 1, d = tid & 1;
        float acc = bp[d];
        for (int k = 0; k < HID; ++k) acc += hb[0][k][r] * Wp[k * DOUT + d];
        u_out[(size_t)(base + r) * DOUT + d] = acc;
    }
}

extern "C" void kernel_launch(void* const* d_in, const int* in_sizes, int n_in,
                              void* d_out, int out_size, void* d_ws, size_t ws_size,
                              hipStream_t stream) {
    const float* vis  = (const float*)d_in[0];
    const float* anet = (const float*)d_in[1];
    const float* Wv   = (const float*)d_in[2];
    const float* bv   = (const float*)d_in[3];
    const float* W0   = (const float*)d_in[4];
    const float* b0   = (const float*)d_in[5];
    const float* W1   = (const float*)d_in[6];
    const float* b1   = (const float*)d_in[7];
    const float* W2   = (const float*)d_in[8];
    const float* b2   = (const float*)d_in[9];
    const float* Wp   = (const float*)d_in[10];
    const float* bp   = (const float*)d_in[11];

    float* xagg  = (float*)d_out;                  // 4096*18
    float* u_out = (float*)d_out + (size_t)N*DIN;  // 4096*2
    float* xall  = (float*)d_ws;                   // 4096*18 scratch

    k_vis<<<(N * DIN + 255) / 256, 256, 0, stream>>>(vis, Wv, bv, xall);
    k_msg<<<N / 8, 256, 0, stream>>>(anet, xall, xagg);
    k_mlp<<<N / 16, 512, 0, stream>>>(xagg, W0, b0, W1, b1, W2, b2, Wp, bp, u_out);
}

// Round 4
// 81.542 us; speedup vs baseline: 1.6327x; 1.1940x over previous
//
#include <hip/hip_runtime.h>
#include <hip/hip_bf16.h>

#define N 4096
#define TSTEPS 3
#define FEAT 36
#define NVIS 6
#define HID 256
#define DIN 18   // TSTEPS*NVIS
#define DOUT 2

#define JT 512      // j-tile staged in LDS (k_msg)

typedef __attribute__((ext_vector_type(8))) short bf16x8;   // 8 bf16 = 4 VGPR
typedef __attribute__((ext_vector_type(4))) float f32x4;

__device__ __forceinline__ short f2bf(float f) {
    unsigned u = __builtin_bit_cast(unsigned, f);
    unsigned r = (u + 0x7FFFu + ((u >> 16) & 1u)) >> 16;   // RNE
    return (short)r;
}

// Collision-free skewed LDS offset for k_msg (verified R3).
__device__ __forceinline__ int srow(int r) {
    return (r >> 5) * 672 + (r & 31) * 20 + ((r >> 2) & 7) * 4;
}

// ---------------- Kernel 1: xall[j][t*6+c] = vis[j,t,:] @ W_vis + b_vis ----
__global__ void k_vis(const float* __restrict__ vis, const float* __restrict__ Wv,
                      const float* __restrict__ bv, float* __restrict__ xall) {
    int o = blockIdx.x * blockDim.x + threadIdx.x;
    if (o >= N * DIN) return;
    int j  = o / DIN;
    int ct = o - j * DIN;
    int t  = ct / NVIS;
    int c  = ct - t * NVIS;
    const float* vrow = vis + (size_t)j * (TSTEPS * FEAT) + t * FEAT;
    float acc = bv[c];
#pragma unroll
    for (int f = 0; f < FEAT; ++f) acc += vrow[f] * Wv[f * NVIS + c];
    xall[o] = acc;
}

// ---------------- Kernel 2: fused 3-timestep message pass (unchanged, R3) ---
__global__ void k_msg(const float* __restrict__ a, const float* __restrict__ xall,
                      float* __restrict__ xagg) {
    __shared__ float xs[16 * 672];
    const int tid  = threadIdx.x;
    const int lane = tid & 63;
    const int wave = tid >> 6;
    const int row_base = blockIdx.x * 8 + wave * 2;

    const float* a0 = a + (size_t)row_base       * (N * 3);
    const float* a1 = a + (size_t)(row_base + 1) * (N * 3);

    float acc[2][3][6];
    float s[2][2];
#pragma unroll
    for (int r = 0; r < 2; ++r) {
#pragma unroll
        for (int t = 0; t < 3; ++t)
#pragma unroll
            for (int c = 0; c < 6; ++c) acc[r][t][c] = 0.f;
        s[r][0] = 0.f; s[r][1] = 0.f;
    }

    for (int tile = 0; tile < N / JT; ++tile) {
        const int tb = tile * JT;
        __syncthreads();
        for (int idx = tid; idx < JT * DIN; idx += 256) {
            int jj = idx / DIN;
            int c  = idx - jj * DIN;
            xs[srow(jj) + c] = xall[(size_t)(tb + jj) * DIN + c];
        }
        __syncthreads();

#pragma unroll
        for (int chunk = 0; chunk < JT / 256; ++chunk) {
            const int jj = chunk * 256 + lane * 4;
            const size_t jb = (size_t)(tb + jj) * 3;
            const float4* pa0 = (const float4*)(a0 + jb);
            const float4* pa1 = (const float4*)(a1 + jb);
            float4 u0 = pa0[0], u1 = pa0[1], u2 = pa0[2];
            float4 v0 = pa1[0], v1 = pa1[1], v2 = pa1[2];
            const float av0[4][3] = {{u0.x,u0.y,u0.z},{u0.w,u1.x,u1.y},
                                     {u1.z,u1.w,u2.x},{u2.y,u2.z,u2.w}};
            const float av1[4][3] = {{v0.x,v0.y,v0.z},{v0.w,v1.x,v1.y},
                                     {v1.z,v1.w,v2.x},{v2.y,v2.z,v2.w}};
#pragma unroll
            for (int q = 0; q < 4; ++q) {
                const float* xr = xs + srow(jj + q);
                float4 x0 = *(const float4*)(xr);
                float4 x1 = *(const float4*)(xr + 4);
                float4 x2 = *(const float4*)(xr + 8);
                float4 x3 = *(const float4*)(xr + 12);
                const float xv[18] = {x0.x,x0.y,x0.z,x0.w, x1.x,x1.y,x1.z,x1.w,
                                      x2.x,x2.y,x2.z,x2.w, x3.x,x3.y,x3.z,x3.w,
                                      xr[16], xr[17]};
#pragma unroll
                for (int t = 0; t < 3; ++t)
#pragma unroll
                    for (int c = 0; c < 6; ++c) {
                        acc[0][t][c] += av0[q][t] * xv[t*6+c];
                        acc[1][t][c] += av1[q][t] * xv[t*6+c];
                    }
                s[0][0] += av0[q][1]; s[0][1] += av0[q][2];
                s[1][0] += av1[q][1]; s[1][1] += av1[q][2];
            }
        }
    }

#pragma unroll
    for (int m = 1; m < 64; m <<= 1) {
#pragma unroll
        for (int r = 0; r < 2; ++r) {
#pragma unroll
            for (int t = 0; t < 3; ++t)
#pragma unroll
                for (int c = 0; c < 6; ++c)
                    acc[r][t][c] += __shfl_xor(acc[r][t][c], m, 64);
            s[r][0] += __shfl_xor(s[r][0], m, 64);
            s[r][1] += __shfl_xor(s[r][1], m, 64);
        }
    }

    if (lane == 0) {
#pragma unroll
        for (int r = 0; r < 2; ++r) {
            const float s1 = s[r][0], s2 = s[r][1];
            float* orow = xagg + (size_t)(row_base + r) * DIN;
#pragma unroll
            for (int c = 0; c < 6; ++c) {
                orow[c]      = acc[r][2][c];
                orow[6 + c]  = acc[r][1][c] * s2;
                orow[12 + c] = acc[r][0][c] * s1 * s2;
            }
        }
    }
}

// ---------------- Weight prep: W1,W2 f32[k][n] -> bf16 B-fragment order -----
// Wp[L][ ((s*16 + j)*64 + l)*8 + jj ] = bf16( W[k][n] ),
//   k = s*32 + (l>>4)*8 + jj, n = j*16 + (l&15).
// MFMA B-frag for (k-step s, n-tile j) is then ONE coalesced b128 per lane.
__global__ void k_wprep(const float* __restrict__ W1, const float* __restrict__ W2,
                        short* __restrict__ Wp) {
    int t = blockIdx.x * 256 + threadIdx.x;      // 0 .. 131071
    int L  = t >> 16;
    int e  = t & 65535;
    int jj = e & 7;
    int l  = (e >> 3) & 63;
    int j  = (e >> 9) & 15;
    int s  = e >> 13;
    int k  = s * 32 + ((l >> 4) << 3) + jj;
    int n  = (j << 4) + (l & 15);
    const float* W = L ? W2 : W1;
    Wp[t] = f2bf(W[k * HID + n]);
}

// ---------------- Kernel 3 (MFMA): MLP 18->256->256->256->2 ----------------
// 256 blocks x 256 thr, 16 rows/block. h tiles in LDS as bf16 [16][256] with
// XOR swizzle idx ^ ((row&7)<<3) -> A-frag ds_read_b128 is conflict-free.
// Each wave computes all 16 rows x its 64-col slice: 4 N-tiles x 8 K-steps.
__global__ void k_mlp_mfma(const float* __restrict__ xagg,
                           const float* __restrict__ W0, const float* __restrict__ b0,
                           const float* __restrict__ b1, const float* __restrict__ b2,
                           const short* __restrict__ Wp,
                           const float* __restrict__ Wpf, const float* __restrict__ bp,
                           float* __restrict__ u_out) {
    __shared__ float  xa[16][DIN];
    __shared__ short  hA[16 * 256];
    __shared__ short  hB[16 * 256];
    __shared__ float  h3[16 * 257];
    const int tid  = threadIdx.x;
    const int lane = tid & 63;
    const int wv   = tid >> 6;        // wave 0..3 -> col slice 64*wv
    const int base = blockIdx.x * 16;

    for (int idx = tid; idx < 16 * DIN; idx += 256) {
        int r = idx / DIN, e = idx - r * DIN;
        xa[r][e] = xagg[(size_t)(base + r) * DIN + e];
    }
    __syncthreads();

    { // ---- layer 0 (K=18, f32 VALU): thread -> 2 rows x 8 neurons ----
        const int g  = tid >> 5;          // 0..7 -> rows 2g,2g+1
        const int n0 = (tid & 31) * 8;
        float acc[2][8];
#pragma unroll
        for (int jn = 0; jn < 8; ++jn) {
            float b = b0[n0 + jn];
            acc[0][jn] = b; acc[1][jn] = b;
        }
        for (int k = 0; k < DIN; ++k) {
            float4 wa = *(const float4*)&W0[k * HID + n0];
            float4 wb = *(const float4*)&W0[k * HID + n0 + 4];
            const float w[8] = {wa.x,wa.y,wa.z,wa.w, wb.x,wb.y,wb.z,wb.w};
            float xr0 = xa[2*g][k], xr1 = xa[2*g+1][k];
#pragma unroll
            for (int jn = 0; jn < 8; ++jn) {
                acc[0][jn] += xr0 * w[jn];
                acc[1][jn] += xr1 * w[jn];
            }
        }
#pragma unroll
        for (int r = 0; r < 2; ++r) {
            int row = 2 * g + r;
            bf16x8 v;
#pragma unroll
            for (int jn = 0; jn < 8; ++jn) v[jn] = f2bf(fmaxf(acc[r][jn], 0.f));
            *(bf16x8*)&hA[(row * 256 + n0) ^ ((row & 7) << 3)] = v;
        }
    }
    __syncthreads();

    // ---- layers 1 & 2: MFMA 16x16x32 bf16 ----
    const int arow = lane & 15;
    const int kgrp = (lane >> 4) << 3;       // 0,8,16,24
#pragma unroll 1
    for (int L = 0; L < 2; ++L) {
        const short* hsrc = L ? hB : hA;
        const float* bias = L ? b2 : b1;
        const short* WpL  = Wp + L * 65536;

        bf16x8 Af[8];
#pragma unroll
        for (int s = 0; s < 8; ++s)
            Af[s] = *(const bf16x8*)&hsrc[(arow * 256 + s * 32 + kgrp) ^ ((arow & 7) << 3)];

        f32x4 acc[4];
#pragma unroll
        for (int jt = 0; jt < 4; ++jt) {
            float b = bias[wv * 64 + jt * 16 + (lane & 15)];
            acc[jt] = (f32x4){b, b, b, b};
        }
#pragma unroll
        for (int s = 0; s < 8; ++s) {
#pragma unroll
            for (int jt = 0; jt < 4; ++jt) {
                int j = wv * 4 + jt;
                bf16x8 Bf = *(const bf16x8*)&WpL[(((s * 16 + j) * 64) + lane) * 8];
                acc[jt] = __builtin_amdgcn_mfma_f32_16x16x32_bf16(Af[s], Bf, acc[jt], 0, 0, 0);
            }
        }
        __syncthreads();   // hB (L=0) may be rewritten / hA reads done
#pragma unroll
        for (int jt = 0; jt < 4; ++jt) {
            int n = wv * 64 + jt * 16 + (lane & 15);
#pragma unroll
            for (int q = 0; q < 4; ++q) {
                int row = ((lane >> 4) << 2) + q;
                float v = fmaxf(acc[jt][q], 0.f);
                if (L == 0) hB[(row * 256 + n) ^ ((row & 7) << 3)] = f2bf(v);
                else        h3[row * 257 + n] = v;
            }
        }
        __syncthreads();
    }

    // ---- final layer 256 -> 2: t = r*16 + d*8 + ks, k-slice of 32 ----
    {
        const int r  = tid >> 4;
        const int d  = (tid >> 3) & 1;
        const int ks = tid & 7;
        float acc = 0.f;
        const float* hr = &h3[r * 257 + ks * 32];
#pragma unroll
        for (int i = 0; i < 32; ++i) acc += hr[i] * Wpf[(ks * 32 + i) * DOUT + d];
        acc += __shfl_xor(acc, 1, 64);
        acc += __shfl_xor(acc, 2, 64);
        acc += __shfl_xor(acc, 4, 64);
        if (ks == 0) u_out[(size_t)(base + r) * DOUT + d] = acc + bp[d];
    }
}

// ---------------- Fallback VALU MLP (R3, used if ws too small) --------------
#define HPITCH 20
__global__ __launch_bounds__(512, 2) void k_mlp(const float* __restrict__ xagg,
                      const float* __restrict__ W0, const float* __restrict__ b0,
                      const float* __restrict__ W1, const float* __restrict__ b1,
                      const float* __restrict__ W2, const float* __restrict__ b2,
                      const float* __restrict__ Wp, const float* __restrict__ bp,
                      float* __restrict__ u_out) {
    __shared__ float xa[16][DIN];
    __shared__ float hb[2][HID][HPITCH];
    const int tid   = threadIdx.x;
    const int n     = tid & 255;
    const int rbase = (tid >> 8) * 8;
    const int base  = blockIdx.x * 16;

    for (int idx = tid; idx < 16 * DIN; idx += 512) {
        int r = idx / DIN, e = idx - r * DIN;
        xa[r][e] = xagg[(size_t)(base + r) * DIN + e];
    }
    __syncthreads();
    {
        float accv[8];
#pragma unroll
        for (int r = 0; r < 8; ++r) accv[r] = b0[n];
        for (int k = 0; k < DIN; ++k) {
            float w = W0[k * HID + n];
#pragma unroll
            for (int r = 0; r < 8; ++r) accv[r] += xa[rbase + r][k] * w;
        }
#pragma unroll
        for (int r = 0; r < 8; ++r) hb[0][n][rbase + r] = fmaxf(accv[r], 0.f);
    }
    __syncthreads();
    {
        float accv[8];
#pragma unroll
        for (int r = 0; r < 8; ++r) accv[r] = b1[n];
        for (int k = 0; k < HID; ++k) {
            float w = W1[k * HID + n];
            const float4* hp = (const float4*)&hb[0][k][rbase];
            float4 h0 = hp[0], h1 = hp[1];
            const float hv[8] = {h0.x,h0.y,h0.z,h0.w, h1.x,h1.y,h1.z,h1.w};
#pragma unroll
            for (int r = 0; r < 8; ++r) accv[r] += hv[r] * w;
        }
#pragma unroll
        for (int r = 0; r < 8; ++r) hb[1][n][rbase + r] = fmaxf(accv[r], 0.f);
    }
    __syncthreads();
    {
        float accv[8];
#pragma unroll
        for (int r = 0; r < 8; ++r) accv[r] = b2[n];
        for (int k = 0; k < HID; ++k) {
            float w = W2[k * HID + n];
            const float4* hp = (const float4*)&hb[1][k][rbase];
            float4 h0 = hp[0], h1 = hp[1];
            const float hv[8] = {h0.x,h0.y,h0.z,h0.w, h1.x,h1.y,h1.z,h1.w};
#pragma unroll
            for (int r = 0; r < 8; ++r) accv[r] += hv[r] * w;
        }
#pragma unroll
        for (int r = 0; r < 8; ++r) hb[0][n][rbase + r] = fmaxf(accv[r], 0.f);
    }
    __syncthreads();
    if (tid < 32) {
        int r = tid >> 1, d = tid & 1;
        float acc = bp[d];
        for (int k = 0; k < HID; ++k) acc += hb[0][k][r] * Wp[k * DOUT + d];
        u_out[(size_t)(base + r) * DOUT + d] = acc;
    }
}

extern "C" void kernel_launch(void* const* d_in, const int* in_sizes, int n_in,
                              void* d_out, int out_size, void* d_ws, size_t ws_size,
                              hipStream_t stream) {
    const float* vis  = (const float*)d_in[0];
    const float* anet = (const float*)d_in[1];
    const float* Wv   = (const float*)d_in[2];
    const float* bv   = (const float*)d_in[3];
    const float* W0   = (const float*)d_in[4];
    const float* b0   = (const float*)d_in[5];
    const float* W1   = (const float*)d_in[6];
    const float* b1   = (const float*)d_in[7];
    const float* W2   = (const float*)d_in[8];
    const float* b2   = (const float*)d_in[9];
    const float* Wp   = (const float*)d_in[10];
    const float* bp   = (const float*)d_in[11];

    float* xagg  = (float*)d_out;                  // 4096*18
    float* u_out = (float*)d_out + (size_t)N*DIN;  // 4096*2
    float* xall  = (float*)d_ws;                   // 4096*18 scratch
    short* Wpk   = (short*)((char*)d_ws + (512 << 10));  // 256 KB bf16 frags

    k_vis<<<(N * DIN + 255) / 256, 256, 0, stream>>>(vis, Wv, bv, xall);
    k_msg<<<N / 8, 256, 0, stream>>>(anet, xall, xagg);

    if (ws_size >= (512 << 10) + 131072 * sizeof(short)) {
        k_wprep<<<512, 256, 0, stream>>>(W1, W2, Wpk);
        k_mlp_mfma<<<N / 16, 256, 0, stream>>>(xagg, W0, b0, b1, b2, Wpk, Wp, bp, u_out);
    } else {
        k_mlp<<<N / 16, 512, 0, stream>>>(xagg, W0, b0, W1, b1, W2, b2, Wp, bp, u_out);
    }
}

// Round 5
// 75.543 us; speedup vs baseline: 1.7623x; 1.0794x over previous
//
#include <hip/hip_runtime.h>

#define N 4096
#define TSTEPS 3
#define FEAT 36
#define NVIS 6
#define HID 256
#define DIN 18   // TSTEPS*NVIS
#define DOUT 2

#define JT 512      // j-tile staged in LDS (streaming phase)

typedef __attribute__((ext_vector_type(8))) short bf16x8;   // 8 bf16 = 4 VGPR
typedef __attribute__((ext_vector_type(4))) float f32x4;

__device__ __forceinline__ short f2bf(float f) {
    unsigned u = __builtin_bit_cast(unsigned, f);
    unsigned r = (u + 0x7FFFu + ((u >> 16) & 1u)) >> 16;   // RNE
    return (short)r;
}

// Collision-free skewed LDS offset for the streaming phase (verified R3/R4).
__device__ __forceinline__ int srow(int r) {
    return (r >> 5) * 672 + (r & 31) * 20 + ((r >> 2) & 7) * 4;
}

// ---------------- Prep (fused): vis->xall  +  W1,W2 -> bf16 B-fragments ----
// blocks [0,288): xall[j][t*6+c] = vis[j,t,:] @ W_vis + b_vis
// blocks [288,800): Wp[((s*16+j)*64+l)*8+jj] = bf16(W[k][n]),
//   k = s*32+(l>>4)*8+jj, n = j*16+(l&15)  (verified R4)
__global__ void k_prep(const float* __restrict__ vis, const float* __restrict__ Wv,
                       const float* __restrict__ bv, float* __restrict__ xall,
                       const float* __restrict__ W1, const float* __restrict__ W2,
                       short* __restrict__ Wp) {
    if (blockIdx.x < 288) {
        int o = blockIdx.x * 256 + threadIdx.x;
        if (o >= N * DIN) return;
        int j  = o / DIN;
        int ct = o - j * DIN;
        int t  = ct / NVIS;
        int c  = ct - t * NVIS;
        const float* vrow = vis + (size_t)j * (TSTEPS * FEAT) + t * FEAT;
        float acc = bv[c];
#pragma unroll
        for (int f = 0; f < FEAT; ++f) acc += vrow[f] * Wv[f * NVIS + c];
        xall[o] = acc;
    } else {
        int t = (blockIdx.x - 288) * 256 + threadIdx.x;   // 0..131071
        int L  = t >> 16;
        int e  = t & 65535;
        int jj = e & 7;
        int l  = (e >> 3) & 63;
        int j  = (e >> 9) & 15;
        int s  = e >> 13;
        int k  = s * 32 + ((l >> 4) << 3) + jj;
        int n  = (j << 4) + (l & 15);
        const float* W = L ? W2 : W1;
        Wp[t] = f2bf(W[k * HID + n]);
    }
}

// ---------------- Fused: 3-timestep message pass + per-row MLP tail ---------
// 512 blocks x 256 thr. Phase A: one streaming pass over a_nets (8 rows/block).
// Phase B (FUSE=1): MLP 18->256->256->256->2 on the block's own 8 rows, MFMA,
// buffers aliased onto the streaming LDS (union) -> occupancy unchanged.
template<int FUSE>
__global__ void k_msg_mlp(const float* __restrict__ a, const float* __restrict__ xall,
                          float* __restrict__ xagg,
                          const short* __restrict__ Wp,
                          const float* __restrict__ W0, const float* __restrict__ b0,
                          const float* __restrict__ b1, const float* __restrict__ b2,
                          const float* __restrict__ Wpf, const float* __restrict__ bp,
                          float* __restrict__ u_out) {
    __shared__ union SM {
        float xs[16 * 672];                       // 43008 B streaming buffer
        struct {
            float xa[8][DIN];                     // block's 8 xagg rows
            short hA[16 * 256];                   // bf16 h, XOR-swizzled rows
            short hB[16 * 256];
            float h3[16 * 257];
        } m;                                      // 33408 B <= union size
    } sm;
    const int tid  = threadIdx.x;
    const int lane = tid & 63;
    const int wave = tid >> 6;
    const int row0 = blockIdx.x * 8;
    const int row_base = row0 + wave * 2;

    const float* a0 = a + (size_t)row_base       * (N * 3);
    const float* a1 = a + (size_t)(row_base + 1) * (N * 3);

    float acc[2][3][6];
    float s[2][2];
#pragma unroll
    for (int r = 0; r < 2; ++r) {
#pragma unroll
        for (int t = 0; t < 3; ++t)
#pragma unroll
            for (int c = 0; c < 6; ++c) acc[r][t][c] = 0.f;
        s[r][0] = 0.f; s[r][1] = 0.f;
    }

    for (int tile = 0; tile < N / JT; ++tile) {
        const int tb = tile * JT;
        __syncthreads();
        for (int idx = tid; idx < JT * DIN; idx += 256) {
            int jj = idx / DIN;
            int c  = idx - jj * DIN;
            sm.xs[srow(jj) + c] = xall[(size_t)(tb + jj) * DIN + c];
        }
        __syncthreads();

#pragma unroll
        for (int chunk = 0; chunk < JT / 256; ++chunk) {
            const int jj = chunk * 256 + lane * 4;
            const size_t jb = (size_t)(tb + jj) * 3;
            const float4* pa0 = (const float4*)(a0 + jb);
            const float4* pa1 = (const float4*)(a1 + jb);
            float4 u0 = pa0[0], u1 = pa0[1], u2 = pa0[2];
            float4 v0 = pa1[0], v1 = pa1[1], v2 = pa1[2];
            const float av0[4][3] = {{u0.x,u0.y,u0.z},{u0.w,u1.x,u1.y},
                                     {u1.z,u1.w,u2.x},{u2.y,u2.z,u2.w}};
            const float av1[4][3] = {{v0.x,v0.y,v0.z},{v0.w,v1.x,v1.y},
                                     {v1.z,v1.w,v2.x},{v2.y,v2.z,v2.w}};
#pragma unroll
            for (int q = 0; q < 4; ++q) {
                const float* xr = sm.xs + srow(jj + q);
                float4 x0 = *(const float4*)(xr);
                float4 x1 = *(const float4*)(xr + 4);
                float4 x2 = *(const float4*)(xr + 8);
                float4 x3 = *(const float4*)(xr + 12);
                const float xv[18] = {x0.x,x0.y,x0.z,x0.w, x1.x,x1.y,x1.z,x1.w,
                                      x2.x,x2.y,x2.z,x2.w, x3.x,x3.y,x3.z,x3.w,
                                      xr[16], xr[17]};
#pragma unroll
                for (int t = 0; t < 3; ++t)
#pragma unroll
                    for (int c = 0; c < 6; ++c) {
                        acc[0][t][c] += av0[q][t] * xv[t*6+c];
                        acc[1][t][c] += av1[q][t] * xv[t*6+c];
                    }
                s[0][0] += av0[q][1]; s[0][1] += av0[q][2];
                s[1][0] += av1[q][1]; s[1][1] += av1[q][2];
            }
        }
    }

    // butterfly reduce (registers only)
#pragma unroll
    for (int m = 1; m < 64; m <<= 1) {
#pragma unroll
        for (int r = 0; r < 2; ++r) {
#pragma unroll
            for (int t = 0; t < 3; ++t)
#pragma unroll
                for (int c = 0; c < 6; ++c)
                    acc[r][t][c] += __shfl_xor(acc[r][t][c], m, 64);
            s[r][0] += __shfl_xor(s[r][0], m, 64);
            s[r][1] += __shfl_xor(s[r][1], m, 64);
        }
    }

    __syncthreads();   // all xs reads done before aliasing the union
    if (lane == 0) {
#pragma unroll
        for (int r = 0; r < 2; ++r) {
            const float s1 = s[r][0], s2 = s[r][1];
            float* xrow = sm.m.xa[wave * 2 + r];
#pragma unroll
            for (int c = 0; c < 6; ++c) {
                xrow[c]      = acc[r][2][c];
                xrow[6 + c]  = acc[r][1][c] * s2;
                xrow[12 + c] = acc[r][0][c] * s1 * s2;
            }
        }
    }
    __syncthreads();

    // coalesced xagg write (8 rows = 144 consecutive floats)
    for (int idx = tid; idx < 8 * DIN; idx += 256) {
        int r = idx / DIN, e = idx - r * DIN;
        xagg[(size_t)(row0 + r) * DIN + e] = sm.m.xa[r][e];
    }

    if (!FUSE) return;

    { // ---- layer 0 (K=18, f32 VALU): thread -> 1 row x 8 neurons ----
        const int row = tid >> 5;            // 0..7
        const int n0  = (tid & 31) * 8;
        float accv[8];
#pragma unroll
        for (int jn = 0; jn < 8; ++jn) accv[jn] = b0[n0 + jn];
        for (int k = 0; k < DIN; ++k) {
            float4 wa = *(const float4*)&W0[k * HID + n0];
            float4 wb = *(const float4*)&W0[k * HID + n0 + 4];
            const float w[8] = {wa.x,wa.y,wa.z,wa.w, wb.x,wb.y,wb.z,wb.w};
            float xr = sm.m.xa[row][k];
#pragma unroll
            for (int jn = 0; jn < 8; ++jn) accv[jn] += xr * w[jn];
        }
        bf16x8 v;
#pragma unroll
        for (int jn = 0; jn < 8; ++jn) v[jn] = f2bf(fmaxf(accv[jn], 0.f));
        *(bf16x8*)&sm.m.hA[(row * 256 + n0) ^ ((row & 7) << 3)] = v;
    }
    __syncthreads();

    // ---- layers 1 & 2: MFMA 16x16x32 bf16 (rows 8-15 garbage, confined) ----
    const int arow = lane & 15;
    const int kgrp = (lane >> 4) << 3;
    const int wv   = wave;
#pragma unroll 1
    for (int L = 0; L < 2; ++L) {
        const short* hsrc = L ? sm.m.hB : sm.m.hA;
        const float* bias = L ? b2 : b1;
        const short* WpL  = Wp + L * 65536;

        bf16x8 Af[8];
#pragma unroll
        for (int ks = 0; ks < 8; ++ks)
            Af[ks] = *(const bf16x8*)&hsrc[(arow * 256 + ks * 32 + kgrp) ^ ((arow & 7) << 3)];

        f32x4 c4[4];
#pragma unroll
        for (int jt = 0; jt < 4; ++jt) {
            float b = bias[wv * 64 + jt * 16 + (lane & 15)];
            c4[jt] = (f32x4){b, b, b, b};
        }
#pragma unroll
        for (int ks = 0; ks < 8; ++ks) {
#pragma unroll
            for (int jt = 0; jt < 4; ++jt) {
                int j = wv * 4 + jt;
                bf16x8 Bf = *(const bf16x8*)&WpL[(((ks * 16 + j) * 64) + lane) * 8];
                c4[jt] = __builtin_amdgcn_mfma_f32_16x16x32_bf16(Af[ks], Bf, c4[jt], 0, 0, 0);
            }
        }
#pragma unroll
        for (int jt = 0; jt < 4; ++jt) {
            int n = wv * 64 + jt * 16 + (lane & 15);
#pragma unroll
            for (int q = 0; q < 4; ++q) {
                int row = ((lane >> 4) << 2) + q;
                float v = fmaxf(c4[jt][q], 0.f);
                if (L == 0) sm.m.hB[(row * 256 + n) ^ ((row & 7) << 3)] = f2bf(v);
                else        sm.m.h3[row * 257 + n] = v;
            }
        }
        __syncthreads();
    }

    // ---- final layer 256 -> 2 for 8 rows: tid = r*16 + d*8 + ks ----
    if (tid < 128) {
        const int r  = tid >> 4;        // 0..7
        const int d  = (tid >> 3) & 1;
        const int ks = tid & 7;
        float accf = 0.f;
        const float* hr = &sm.m.h3[r * 257 + ks * 32];
#pragma unroll
        for (int i = 0; i < 32; ++i) accf += hr[i] * Wpf[(ks * 32 + i) * DOUT + d];
        accf += __shfl_xor(accf, 1, 64);
        accf += __shfl_xor(accf, 2, 64);
        accf += __shfl_xor(accf, 4, 64);
        if (ks == 0) u_out[(size_t)(row0 + r) * DOUT + d] = accf + bp[d];
    }
}

// ---------------- Fallback VALU MLP (only if workspace too small) -----------
#define HPITCH 20
__global__ __launch_bounds__(512, 2) void k_mlp(const float* __restrict__ xagg,
                      const float* __restrict__ W0, const float* __restrict__ b0,
                      const float* __restrict__ W1, const float* __restrict__ b1,
                      const float* __restrict__ W2, const float* __restrict__ b2,
                      const float* __restrict__ Wpf, const float* __restrict__ bp,
                      float* __restrict__ u_out) {
    __shared__ float xa[16][DIN];
    __shared__ float hb[2][HID][HPITCH];
    const int tid   = threadIdx.x;
    const int n     = tid & 255;
    const int rbase = (tid >> 8) * 8;
    const int base  = blockIdx.x * 16;

    for (int idx = tid; idx < 16 * DIN; idx += 512) {
        int r = idx / DIN, e = idx - r * DIN;
        xa[r][e] = xagg[(size_t)(base + r) * DIN + e];
    }
    __syncthreads();
    {
        float accv[8];
#pragma unroll
        for (int r = 0; r < 8; ++r) accv[r] = b0[n];
        for (int k = 0; k < DIN; ++k) {
            float w = W0[k * HID + n];
#pragma unroll
            for (int r = 0; r < 8; ++r) accv[r] += xa[rbase + r][k] * w;
        }
#pragma unroll
        for (int r = 0; r < 8; ++r) hb[0][n][rbase + r] = fmaxf(accv[r], 0.f);
    }
    __syncthreads();
    {
        float accv[8];
#pragma unroll
        for (int r = 0; r < 8; ++r) accv[r] = b1[n];
        for (int k = 0; k < HID; ++k) {
            float w = W1[k * HID + n];
            const float4* hp = (const float4*)&hb[0][k][rbase];
            float4 h0 = hp[0], h1 = hp[1];
            const float hv[8] = {h0.x,h0.y,h0.z,h0.w, h1.x,h1.y,h1.z,h1.w};
#pragma unroll
            for (int r = 0; r < 8; ++r) accv[r] += hv[r] * w;
        }
#pragma unroll
        for (int r = 0; r < 8; ++r) hb[1][n][rbase + r] = fmaxf(accv[r], 0.f);
    }
    __syncthreads();
    {
        float accv[8];
#pragma unroll
        for (int r = 0; r < 8; ++r) accv[r] = b2[n];
        for (int k = 0; k < HID; ++k) {
            float w = W2[k * HID + n];
            const float4* hp = (const float4*)&hb[1][k][rbase];
            float4 h0 = hp[0], h1 = hp[1];
            const float hv[8] = {h0.x,h0.y,h0.z,h0.w, h1.x,h1.y,h1.z,h1.w};
#pragma unroll
            for (int r = 0; r < 8; ++r) accv[r] += hv[r] * w;
        }
#pragma unroll
        for (int r = 0; r < 8; ++r) hb[0][n][rbase + r] = fmaxf(accv[r], 0.f);
    }
    __syncthreads();
    if (tid < 32) {
        int r = tid >> 1, d = tid & 1;
        float acc = bp[d];
        for (int k = 0; k < HID; ++k) acc += hb[0][k][r] * Wpf[k * DOUT + d];
        u_out[(size_t)(base + r) * DOUT + d] = acc;
    }
}

extern "C" void kernel_launch(void* const* d_in, const int* in_sizes, int n_in,
                              void* d_out, int out_size, void* d_ws, size_t ws_size,
                              hipStream_t stream) {
    const float* vis  = (const float*)d_in[0];
    const float* anet = (const float*)d_in[1];
    const float* Wv   = (const float*)d_in[2];
    const float* bv   = (const float*)d_in[3];
    const float* W0   = (const float*)d_in[4];
    const float* b0   = (const float*)d_in[5];
    const float* W1   = (const float*)d_in[6];
    const float* b1   = (const float*)d_in[7];
    const float* W2   = (const float*)d_in[8];
    const float* b2   = (const float*)d_in[9];
    const float* Wpf  = (const float*)d_in[10];
    const float* bp   = (const float*)d_in[11];

    float* xagg  = (float*)d_out;                  // 4096*18
    float* u_out = (float*)d_out + (size_t)N*DIN;  // 4096*2
    float* xall  = (float*)d_ws;                   // 4096*18 scratch (288 KB)
    short* Wpk   = (short*)((char*)d_ws + (512 << 10));  // 256 KB bf16 frags

    const bool fuse = ws_size >= (512 << 10) + 131072 * sizeof(short);

    if (fuse) {
        k_prep<<<800, 256, 0, stream>>>(vis, Wv, bv, xall, W1, W2, Wpk);
        k_msg_mlp<1><<<N / 8, 256, 0, stream>>>(anet, xall, xagg, Wpk,
                                                W0, b0, b1, b2, Wpf, bp, u_out);
    } else {
        k_prep<<<288, 256, 0, stream>>>(vis, Wv, bv, xall, W1, W2, Wpk);
        k_msg_mlp<0><<<N / 8, 256, 0, stream>>>(anet, xall, xagg, Wpk,
                                                W0, b0, b1, b2, Wpf, bp, u_out);
        k_mlp<<<N / 16, 512, 0, stream>>>(xagg, W0, b0, W1, b1, W2, b2, Wpf, bp, u_out);
    }
}